// Round 2
// baseline (3787.929 us; speedup 1.0000x reference)
//
#include <hip/hip_runtime.h>
#include <math.h>

// Problem constants
#define BB   64
#define LL   720
#define CC   512
#define FF   361
#define KTOP 20

// ---------------------------------------------------------------------------
// Generic batched tile transpose: in (z, R, Cc) -> out (z, Cc, R)
// grid: (ceil(Cc/32), ceil(R/32), batch), block (32,8)
// ---------------------------------------------------------------------------
__global__ __launch_bounds__(256) void transpose_kernel(
    const float* __restrict__ in, float* __restrict__ out,
    int R, int Cc, long sIn, long sOut) {
  __shared__ float tile[32][33];
  const float* inp = in + (long)blockIdx.z * sIn;
  float* outp = out + (long)blockIdx.z * sOut;
  int r0 = blockIdx.y * 32, c0 = blockIdx.x * 32;
  int tx = threadIdx.x, ty = threadIdx.y;
#pragma unroll
  for (int i = 0; i < 4; ++i) {
    int r = r0 + ty + 8 * i, c = c0 + tx;
    if (r < R && c < Cc) tile[ty + 8 * i][tx] = inp[(long)r * Cc + c];
  }
  __syncthreads();
#pragma unroll
  for (int i = 0; i < 4; ++i) {
    int c = c0 + ty + 8 * i, r = r0 + tx;
    if (c < Cc && r < R) outp[(long)c * R + r] = tile[tx][ty + 8 * i];
  }
}

// ---------------------------------------------------------------------------
// residual[b,l,c] = x[b,l,c] - xfilt[b,c,l]   (transpose-subtract)
// grid: (16, 23, 64), block (32,8)
// ---------------------------------------------------------------------------
__global__ __launch_bounds__(256) void residual_kernel(
    const float* __restrict__ x, const float* __restrict__ xf,
    float* __restrict__ out) {
  __shared__ float tile[32][33];
  int b = blockIdx.z;
  const float* xfp = xf + (long)b * CC * LL;
  int c0 = blockIdx.x * 32, l0 = blockIdx.y * 32;
  int tx = threadIdx.x, ty = threadIdx.y;
#pragma unroll
  for (int i = 0; i < 4; ++i) {
    int c = c0 + ty + 8 * i, l = l0 + tx;
    if (l < LL) tile[ty + 8 * i][tx] = xfp[(long)c * LL + l];
  }
  __syncthreads();
  long xbase = (long)b * LL * CC;
#pragma unroll
  for (int i = 0; i < 4; ++i) {
    int l = l0 + ty + 8 * i, c = c0 + tx;
    if (l < LL) {
      long off = xbase + (long)l * CC + c;
      out[off] = x[off] - tile[tx][ty + 8 * i];
    }
  }
}

// ---------------------------------------------------------------------------
// Per-series DFT (361 freqs) + top-20 magnitude filter + reconstruction.
// fp64-exact: double twiddle table + double accumulation so top-k ranking
// matches the fp64 reference ranking (boundary gaps can be ~1e-6 relative;
// one swap costs ~0.25 absmax which fails the 0.1625 threshold).
// One block per (b,c) series. 32768 blocks x 256 threads.
// ---------------------------------------------------------------------------
__global__ __launch_bounds__(256) void dft_topk_kernel(
    const float* __restrict__ xt, float* __restrict__ xfilt) {
  __shared__ float  sx[720];
  __shared__ double ct[1260];   // cos(j*2pi/720); sin(k*2pi/720)=ct[k+540], k<720
  __shared__ float  se[368];
  __shared__ float  so[368];
  __shared__ double sre[368];
  __shared__ double sim[368];
  __shared__ double smag[368];
  __shared__ int    ssel[KTOP];
  __shared__ double swv[4];
  __shared__ int    swi[4];

  const int tid = threadIdx.x;
  const long base = (long)blockIdx.x * LL;

  for (int t = tid; t < LL; t += 256) sx[t] = xt[base + t];
  const double W0d = 8.7266462599716478846e-3;  // 2*pi/720
  for (int j = tid; j < 1260; j += 256) {
    int j2 = (j >= 720) ? j - 720 : j;
    ct[j] = cos((double)j2 * W0d);
  }
  __syncthreads();
  // even/odd fold: Re uses e[t]=x[t]+x[L-t], Im uses o[t]=x[t]-x[L-t]
  for (int t = tid; t < FF; t += 256) {
    if (t == 0)        { se[0] = sx[0];     so[0] = 0.f; }
    else if (t == 360) { se[360] = sx[360]; so[360] = 0.f; }
    else               { se[t] = sx[t] + sx[LL - t]; so[t] = sx[t] - sx[LL - t]; }
  }
  __syncthreads();

  // Each thread computes freq f1=tid and (if valid) f2=tid+256 with exact
  // table twiddles, double accumulation.
  const int f1 = tid, f2 = tid + 256;
  const bool h2 = (f2 < FF);
  double re1 = (double)se[0], im1 = 0.0;
  double re2 = (double)se[0], im2 = 0.0;
  int k1 = 0, k2 = 0;
  for (int t = 1; t < 360; ++t) {
    k1 += f1; if (k1 >= 720) k1 -= 720;
    double e = (double)se[t], o = (double)so[t];
    re1 += e * ct[k1];
    im1 -= o * ct[k1 + 540];
    if (h2) {
      k2 += f2; if (k2 >= 720) k2 -= 720;
      re2 += e * ct[k2];
      im2 -= o * ct[k2 + 540];
    }
  }
  // t = 360 term: cos(pi*f) = (-1)^f, sin = 0
  re1 += (f1 & 1) ? -(double)se[360] : (double)se[360];
  if (h2) re2 += (f2 & 1) ? -(double)se[360] : (double)se[360];

  sre[f1] = re1; sim[f1] = im1; smag[f1] = re1 * re1 + im1 * im1;
  if (h2) { sre[f2] = re2; sim[f2] = im2; smag[f2] = re2 * re2 + im2 * im2; }
  __syncthreads();

  // top-20 by repeated argmax (ties -> lower index, matching lax.top_k)
  for (int it = 0; it < KTOP; ++it) {
    double v = smag[tid]; int bi = tid;
    if (h2) {
      double v2 = smag[f2];
      if (v2 > v) { v = v2; bi = f2; }
    }
#pragma unroll
    for (int off = 32; off > 0; off >>= 1) {
      double ov = __shfl_down(v, off);
      int oi = __shfl_down(bi, off);
      if (ov > v || (ov == v && oi < bi)) { v = ov; bi = oi; }
    }
    if ((tid & 63) == 0) { swv[tid >> 6] = v; swi[tid >> 6] = bi; }
    __syncthreads();
    if (tid == 0) {
      double bv = swv[0]; int bb = swi[0];
      for (int w = 1; w < 4; ++w) {
        if (swv[w] > bv || (swv[w] == bv && swi[w] < bb)) { bv = swv[w]; bb = swi[w]; }
      }
      ssel[it] = bb;
      smag[bb] = -1.0;
    }
    __syncthreads();
  }

  // reconstruct: x_filt[t] = (1/L) * sum_f w_f (Re_f cos - Im_f sin)
  const double invL = 1.0 / 720.0;
  for (int t = tid; t < LL; t += 256) {
    double acc = 0.0;
#pragma unroll
    for (int it = 0; it < KTOP; ++it) {
      int f = ssel[it];
      int k = (f * t) % LL;
      double cv = ct[k];
      double sv = ct[k + 540];
      double w = (f == 0 || f == 360) ? 1.0 : 2.0;
      acc += w * (sre[f] * cv - sim[f] * sv);
    }
    xfilt[base + t] = (float)(acc * invL);
  }
}

// ---------------------------------------------------------------------------
// fp32 tiled GEMM: Cout = epilogue(A[M,K] @ W[K,N]).
// BM=BN=64, BK=16, 256 threads, 4x4 acc per thread.
// EPI: 0 = store (acc+bias)
//      1 = store relu(acc+bias)
//      2 = store relu(acc+bias+Cin)
//      3 = store Cin + relu(acc+bias)
// BIASM: 0 none, 1 per-column, 2 per-row
// grid: (N/64, ceil(M/64), batch); strides sA/sW/sC applied per blockIdx.z.
// ---------------------------------------------------------------------------
template <int EPI, int BIASM>
__global__ __launch_bounds__(256) void gemm_f32(
    const float* __restrict__ A, const float* __restrict__ W,
    const float* __restrict__ bias, const float* __restrict__ Cin,
    float* __restrict__ Cout, int M, int N, int K,
    long sA, long sW, long sC) {
  __shared__ float As[16][68];
  __shared__ float Ws[16][68];
  A += (long)blockIdx.z * sA;
  W += (long)blockIdx.z * sW;
  Cin += (long)blockIdx.z * sC;
  Cout += (long)blockIdx.z * sC;
  const int m0 = blockIdx.y * 64, n0 = blockIdx.x * 64;
  const int tid = threadIdx.x;
  const int tx = tid & 15, ty = tid >> 4;
  const int arow = tid >> 2, ac = (tid & 3) * 4;
  const int wrow = tid >> 4, wc = (tid & 15) * 4;

  float acc[4][4] = {};
  for (int k0 = 0; k0 < K; k0 += 16) {
    float4 av;
    int gr = m0 + arow;
    if (gr < M) av = *(const float4*)&A[(long)gr * K + k0 + ac];
    else        av = make_float4(0.f, 0.f, 0.f, 0.f);
    float4 wv = *(const float4*)&W[(long)(k0 + wrow) * N + n0 + wc];
    __syncthreads();
    As[ac + 0][arow] = av.x; As[ac + 1][arow] = av.y;
    As[ac + 2][arow] = av.z; As[ac + 3][arow] = av.w;
    *(float4*)&Ws[wrow][wc] = wv;
    __syncthreads();
#pragma unroll
    for (int kk = 0; kk < 16; ++kk) {
      float4 a = *(const float4*)&As[kk][ty * 4];
      float4 b = *(const float4*)&Ws[kk][tx * 4];
      float aa[4] = {a.x, a.y, a.z, a.w};
      float bb[4] = {b.x, b.y, b.z, b.w};
#pragma unroll
      for (int i = 0; i < 4; ++i)
#pragma unroll
        for (int j = 0; j < 4; ++j)
          acc[i][j] = fmaf(aa[i], bb[j], acc[i][j]);
    }
  }

#pragma unroll
  for (int i = 0; i < 4; ++i) {
    int r = m0 + ty * 4 + i;
    if (r >= M) continue;
    float rb = (BIASM == 2) ? bias[r] : 0.f;
#pragma unroll
    for (int j = 0; j < 4; ++j) {
      int cix = n0 + tx * 4 + j;
      float v = acc[i][j];
      if (BIASM == 1) v += bias[cix];
      if (BIASM == 2) v += rb;
      long off = (long)r * N + cix;
      if (EPI == 0) Cout[off] = v;
      else if (EPI == 1) Cout[off] = fmaxf(v, 0.f);
      else if (EPI == 2) Cout[off] = fmaxf(v + Cin[off], 0.f);
      else Cout[off] = Cin[off] + fmaxf(v, 0.f);
    }
  }
}

// ---------------------------------------------------------------------------
extern "C" void kernel_launch(void* const* d_in, const int* in_sizes, int n_in,
                              void* d_out, int out_size, void* d_ws, size_t ws_size,
                              hipStream_t stream) {
  const float* x      = (const float*)d_in[0];
  const float* w_freq = (const float*)d_in[1];
  const float* b_freq = (const float*)d_in[2];
  const float* w_all1 = (const float*)d_in[3];
  const float* b_all1 = (const float*)d_in[4];
  const float* w_all2 = (const float*)d_in[5];
  const float* b_all2 = (const float*)d_in[6];
  const float* w_time = (const float*)d_in[7];
  const float* b_time = (const float*)d_in[8];
  const float* w_chan = (const float*)d_in[9];
  const float* b_chan = (const float*)d_in[10];
  const float* w_proj = (const float*)d_in[11];
  const float* b_proj = (const float*)d_in[12];

  float* out0 = (float*)d_out;                       // residual (64,720,512)
  float* out1 = out0 + (size_t)BB * LL * CC;         // pred     (64,720,512)

  // workspace layout (floats). Peak ~214.6 MB.
  float* ws  = (float*)d_ws;
  float* XT  = ws;                    // (64,512,720)  23,592,960
  float* XF  = XT + 23592960;         // (64,512,720)  23,592,960
  float* H   = XF + 23592960;         // (32768,64)     2,097,152
  float* A1  = H + 2097152;           // (32768,128)    4,194,304
  float* WPT = A1 + 4194304;          // (720,256)        184,320
  float* Z   = XF;                    // reuse XF after h-GEMM: (32768,256)
  float* T   = XF + 8388608;          // (32768,256)
  float* TT  = XT;                    // reuse XT after a1-GEMM: (64,256,512)
  float* CO  = XT + 8388608;          // (64,256,512)

  dim3 tb(32, 8);

  // 1) x (b,720,512) -> XT (b,512,720)
  transpose_kernel<<<dim3(16, 23, BB), tb, 0, stream>>>(
      x, XT, LL, CC, (long)LL * CC, (long)LL * CC);
  // 2) w_proj (256,720) -> WPT (720,256)
  transpose_kernel<<<dim3(23, 8, 1), tb, 0, stream>>>(
      w_proj, WPT, 256, 720, 0, 0);
  // 3) per-series DFT + top-20 filter -> XF (b,512,720)
  dft_topk_kernel<<<BB * CC, 256, 0, stream>>>(XT, XF);
  // 4) residual = x - XF^T -> out0
  residual_kernel<<<dim3(16, 23, BB), tb, 0, stream>>>(x, XF, out0);
  // 5) h = relu(XF @ w_freq + b_freq)            (32768,720)x(720,64)
  gemm_f32<1, 1><<<dim3(1, 512, 1), 256, 0, stream>>>(
      XF, w_freq, b_freq, nullptr, H, 32768, 64, 720, 0, 0, 0);
  // 6) tmp = h @ w_all1[:64]                     (32768,64)x(64,128)
  gemm_f32<0, 0><<<dim3(2, 512, 1), 256, 0, stream>>>(
      H, w_all1, nullptr, nullptr, A1, 32768, 128, 64, 0, 0, 0);
  // 7) a1 = relu(tmp + XT @ w_all1[64:] + b_all1) (32768,720)x(720,128)
  gemm_f32<2, 1><<<dim3(2, 512, 1), 256, 0, stream>>>(
      XT, w_all1 + 64 * 128, b_all1, A1, A1, 32768, 128, 720, 0, 0, 0);
  // 8) z = a1 @ w_all2 + b_all2                  (32768,128)x(128,256)
  gemm_f32<0, 1><<<dim3(4, 512, 1), 256, 0, stream>>>(
      A1, w_all2, b_all2, nullptr, Z, 32768, 256, 128, 0, 0, 0);
  // 9) t = z + relu(z @ w_time + b_time)         (32768,256)x(256,256)
  gemm_f32<3, 1><<<dim3(4, 512, 1), 256, 0, stream>>>(
      Z, w_time, b_time, Z, T, 32768, 256, 256, 0, 0, 0);
  // 10) T (b,512,256) -> TT (b,256,512)
  transpose_kernel<<<dim3(8, 16, BB), tb, 0, stream>>>(
      T, TT, 512, 256, (long)512 * 256, (long)512 * 256);
  // 11) c = TT + relu(TT @ w_chan + b_chan)      (16384,512)x(512,512)
  gemm_f32<3, 1><<<dim3(8, 256, 1), 256, 0, stream>>>(
      TT, w_chan, b_chan, TT, CO, 16384, 512, 512, 0, 0, 0);
  // 12) pred[b,p,c] = WPT[p,:] @ CO[b,:,c] + b_proj[p]  (720,256)x(256,512) x64
  gemm_f32<0, 2><<<dim3(8, 12, BB), 256, 0, stream>>>(
      WPT, CO, b_proj, nullptr, out1, 720, 512, 256,
      0, (long)256 * 512, (long)LL * CC);
}